// Round 6
// baseline (275.380 us; speedup 1.0000x reference)
//
#include <hip/hip_runtime.h>
#include <math.h>

// Problem: B=4, S=4096, H=2048, E=64, K=8; T = 16384 tokens.
#define HDIM 2048
#define TTOK 16384
#define NEXP 64
#define TOPK 8
#define SLEN 4096
#define NBATCH 4
#define KS 8
#define KR 256                // k per split
#define PARTSZ (NEXP * TTOK)  // floats per k-split partial (4 MB)

// Output layout (flat, float32):
#define OFF_W    131072
#define OFF_LOSS 262144
#define OFF_LOAD 262145

// ws layout (float offsets): Pacc[4][64] @0, Cacc[4][64] @256, counter @512,
// Wt [2048][64] @1024, partials @WS_PART (KS x [64][16384]).
#define WS_PACC 0
#define WS_CACC 256
#define WS_CNT  512
#define WS_WT   1024
#define WS_PART (1024 + HDIM * NEXP)

// ---------------------------------------------------------------------------
// LDS-tiled transpose W [64][2048] -> Wt [2048][64] (R2-proven).
__global__ __launch_bounds__(256) void transpose_w(const float* __restrict__ W,
                                                   float* __restrict__ Wt) {
  __shared__ float tile[64][65];
  const int tid = threadIdx.x;
  const int k0 = blockIdx.x * 64;
  {
    const int kc = (tid & 15) << 2;
    const int er = tid >> 4;
#pragma unroll
    for (int i = 0; i < 4; ++i) {
      int e = er + i * 16;
      float4 v = *(const float4*)(W + (size_t)e * HDIM + k0 + kc);
      tile[e][kc + 0] = v.x; tile[e][kc + 1] = v.y;
      tile[e][kc + 2] = v.z; tile[e][kc + 3] = v.w;
    }
  }
  __syncthreads();
  {
    const int e4 = (tid & 15) << 2;
    const int kr = tid >> 4;
#pragma unroll
    for (int i = 0; i < 4; ++i) {
      int k = kr + i * 16;
      float4 v;
      v.x = tile[e4 + 0][k]; v.y = tile[e4 + 1][k];
      v.z = tile[e4 + 2][k]; v.w = tile[e4 + 3][k];
      *(float4*)(Wt + (size_t)(k0 + k) * NEXP + e4) = v;
    }
  }
}

// ---------------------------------------------------------------------------
// GEMM: grid 1024 = 128 token-groups x 8 k-splits; block 256 = 4 waves.
// Wave w -> experts [16w,16w+16); each lane owns TWO tokens (lane, lane+64)
// so one s_load_dwordx16 W-chunk feeds 32 FMAs (halves SMEM stall vs R5).
// x tile [128 tok][32 k] in LDS, granule-XOR swizzle; 2 ds_read_b128 per
// granule step feed 128 FMAs. Per-token k order ascending within split.
__global__ __launch_bounds__(256, 4) void gate_gemm(
    const float* __restrict__ x,    // [16384][2048]
    const float* __restrict__ Wt,   // [2048][64]
    float* __restrict__ part) {     // KS x [64][16384]
  __shared__ float xs[2][128 * 32];  // 32 KB double buffer

  const int tid = threadIdx.x;
  const int lane = tid & 63;
  const int wv = __builtin_amdgcn_readfirstlane(tid >> 6);  // 0..3
  const int e0 = wv << 4;
  const int bid = blockIdx.x;
  const int kh = bid & 7;
  const int tg = bid >> 3;      // 0..127
  const int tok0 = tg << 7;     // 128 tokens/block
  const int kb = kh << 8;       // 256-k split

  float acc0[16], acc1[16];
#pragma unroll
  for (int j = 0; j < 16; ++j) { acc0[j] = 0.f; acc1[j] = 0.f; }

  // staging: thread -> token row sr, half sh (16 consecutive floats)
  const int sr = tid >> 1;      // 0..127
  const int sh = tid & 1;       // 0..1
  const float* xp = x + (size_t)(tok0 + sr) * HDIM + kb + (sh << 4);
  float4 a[4];
#pragma unroll
  for (int i = 0; i < 4; ++i) a[i] = *(const float4*)(xp + (i << 2));

  const int s0 = lane & 7;              // read-side XOR (same for lane+64)
  const int r0 = lane << 5;
  const int r1 = (lane + 64) << 5;
  const int sbase = sr << 5;
  const int s7 = sr & 7;

  for (int kt = 0; kt < 8; ++kt) {
    float* xb = &xs[kt & 1][0];
#pragma unroll
    for (int i = 0; i < 4; ++i) {
      const int g = (sh << 2) + i;                 // logical granule 0..7
      *(float4*)&xb[sbase + ((g ^ s7) << 2)] = a[i];
    }
    __syncthreads();  // single barrier/tile; next store -> other buffer
    if (kt < 7) {
      const float* np_ = xp + ((kt + 1) << 5);
#pragma unroll
      for (int i = 0; i < 4; ++i) a[i] = *(const float4*)(np_ + (i << 2));
    }
    const float* wkb = Wt + ((size_t)(kb + (kt << 5)) << 6) + e0;
#pragma unroll
    for (int c = 0; c < 8; ++c) {
      float4 xv0 = *(const float4*)&xb[r0 + ((c ^ s0) << 2)];
      float4 xv1 = *(const float4*)&xb[r1 + ((c ^ s0) << 2)];
      const float xf0[4] = {xv0.x, xv0.y, xv0.z, xv0.w};
      const float xf1[4] = {xv1.x, xv1.y, xv1.z, xv1.w};
#pragma unroll
      for (int q = 0; q < 4; ++q) {
        const float* wr = wkb + (((c << 2) + q) << 6);  // uniform -> s_load_x16
        const float xa = xf0[q];
        const float xc = xf1[q];
#pragma unroll
        for (int j = 0; j < 16; ++j) {
          acc0[j] = fmaf(xa, wr[j], acc0[j]);
          acc1[j] = fmaf(xc, wr[j], acc1[j]);
        }
      }
    }
  }

  // partial store [kh][e][tok]: 64-lane coalesced dwords, two token sets
  float* dst = part + (size_t)kh * PARTSZ + (size_t)e0 * TTOK + tok0 + lane;
#pragma unroll
  for (int j = 0; j < 16; ++j) {
    dst[(size_t)j * TTOK] = acc0[j];
    dst[(size_t)j * TTOK + 64] = acc1[j];
  }
}

// ---------------------------------------------------------------------------
// Epilogue: grid 128 x 128 thr; thread = token in every phase.
// le rows stride 65 (odd) -> phase-2 row reads 2-way (free), phase-3 column
// reads conflict-free. Finalize fused via device-scope atomic counter.
__global__ __launch_bounds__(128) void gate_epilogue(
    const float* __restrict__ part, const float* __restrict__ bias,
    float* __restrict__ out, float* __restrict__ Pacc,
    float* __restrict__ Cacc, int* __restrict__ counter) {
  __shared__ float le[128 * 65];   // [tok][e], odd stride
  __shared__ float rinv_sh[128];
  __shared__ float psum[64];
  __shared__ unsigned csum[64];
  __shared__ int lastf;

  const int tid = threadIdx.x;
  const int t0 = blockIdx.x << 7;   // 128 tokens/block

  if (tid < 64) { psum[tid] = 0.f; csum[tid] = 0u; }

  // phase 1: 2048 float4-columns, 16/thread; pairwise tree over 8 splits
#pragma unroll
  for (int i = 0; i < 16; ++i) {
    const int idx = (i << 7) + tid;
    const int e = idx >> 5;
    const int q = idx & 31;
    const float* p = part + (size_t)e * TTOK + t0 + (q << 2);
    float4 v[KS];
#pragma unroll
    for (int s = 0; s < KS; ++s) v[s] = *(const float4*)(p + (size_t)s * PARTSZ);
    float r[4];
    const float* f = (const float*)v;
#pragma unroll
    for (int j = 0; j < 4; ++j)
      r[j] = ((f[j] + f[4 + j]) + (f[8 + j] + f[12 + j])) +
             ((f[16 + j] + f[20 + j]) + (f[24 + j] + f[28 + j]));
#pragma unroll
    for (int j = 0; j < 4; ++j) le[((q << 2) + j) * 65 + e] = r[j];
  }
  __syncthreads();

  // phase 2: per-token sigmoid sum, top-8, outputs
  {
    float bl[64];
    float ssum = 0.f;
#pragma unroll
    for (int e = 0; e < NEXP; ++e) {
      float l = le[tid * 65 + e];
      ssum += 1.f / (1.f + expf(-l));
      bl[e] = l + bias[e];
    }
    rinv_sh[tid] = 1.f / (ssum + 1e-10f);

    unsigned long long chosen = 0ull;
    int i8[TOPK];
    float w8[TOPK];
    float wsum = 0.f;
#pragma unroll
    for (int j = 0; j < TOPK; ++j) {
      float best = -1e30f;
      int bi = 0;
      float braw = 0.f;
#pragma unroll
      for (int e = 0; e < NEXP; ++e) {
        bool ok = (((chosen >> e) & 1ull) == 0ull) && (bl[e] > best);
        if (ok) { best = bl[e]; bi = e; braw = bl[e] - bias[e]; }
      }
      chosen |= (1ull << bi);
      float sc = 1.f / (1.f + expf(-braw));
      i8[j] = bi;
      w8[j] = sc;
      wsum += sc;
    }
    const float inv = 1.f / (wsum + 1e-10f);
    const int t = t0 + tid;
    float4 o;
    o.x = (float)i8[0]; o.y = (float)i8[1]; o.z = (float)i8[2]; o.w = (float)i8[3];
    *(float4*)(out + (size_t)t * TOPK) = o;
    o.x = (float)i8[4]; o.y = (float)i8[5]; o.z = (float)i8[6]; o.w = (float)i8[7];
    *(float4*)(out + (size_t)t * TOPK + 4) = o;
    o.x = w8[0] * inv; o.y = w8[1] * inv; o.z = w8[2] * inv; o.w = w8[3] * inv;
    *(float4*)(out + OFF_W + (size_t)t * TOPK) = o;
    o.x = w8[4] * inv; o.y = w8[5] * inv; o.z = w8[6] * inv; o.w = w8[7] * inv;
    *(float4*)(out + OFF_W + (size_t)t * TOPK + 4) = o;
#pragma unroll
    for (int j = 0; j < TOPK; ++j) atomicAdd(&csum[i8[j]], 1u);
  }
  __syncthreads();

  // phase 3: thread (e = tid&63, chunk = tid>>6) sums normalized scores
  {
    const int e = tid & 63;
    const int ch = tid >> 6;
    float p = 0.f;
#pragma unroll 8
    for (int tt = 0; tt < 64; ++tt) {
      const int tok = (ch << 6) + tt;
      float sc = 1.f / (1.f + expf(-le[tok * 65 + e]));
      p += sc * rinv_sh[tok];
    }
    atomicAdd(&psum[e], p);
  }
  __syncthreads();

  const int b = blockIdx.x >> 5;  // 32 blocks of 128 tokens per batch
  if (tid < 64) {
    atomicAdd(&Pacc[(b << 6) + tid], psum[tid]);
    atomicAdd(&Cacc[(b << 6) + tid], (float)csum[tid]);
  }
  __syncthreads();
  __threadfence();
  if (tid == 0) {
    int old = __hip_atomic_fetch_add(counter, 1, __ATOMIC_ACQ_REL,
                                     __HIP_MEMORY_SCOPE_AGENT);
    lastf = (old == 127) ? 1 : 0;
  }
  __syncthreads();

  if (lastf && tid < 64) {
    const int e = tid;
    float load = 0.f, partl = 0.f;
#pragma unroll
    for (int bb = 0; bb < NBATCH; ++bb) {
      float c = __hip_atomic_load(&Cacc[(bb << 6) + e], __ATOMIC_RELAXED,
                                  __HIP_MEMORY_SCOPE_AGENT);
      float p = __hip_atomic_load(&Pacc[(bb << 6) + e], __ATOMIC_RELAXED,
                                  __HIP_MEMORY_SCOPE_AGENT);
      load += c;
      partl += (c * (1.f / (TOPK * (float)SLEN))) * (p * (1.f / (float)SLEN));
    }
    out[OFF_LOAD + e] = load;
#pragma unroll
    for (int off = 32; off; off >>= 1) partl += __shfl_down(partl, off);
    if (e == 0) out[OFF_LOSS] = 0.01f * partl * (1.f / (float)NBATCH);
  }
}

// ---------------------------------------------------------------------------
extern "C" void kernel_launch(void* const* d_in, const int* in_sizes, int n_in,
                              void* d_out, int out_size, void* d_ws, size_t ws_size,
                              hipStream_t stream) {
  const float* x = (const float*)d_in[0];     // [4,4096,2048]
  const float* W = (const float*)d_in[1];     // [64,2048]
  const float* bias = (const float*)d_in[2];  // [64]
  float* out = (float*)d_out;

  float* ws = (float*)d_ws;
  float* Pacc = ws + WS_PACC;
  float* Cacc = ws + WS_CACC;
  int* counter = (int*)(ws + WS_CNT);
  float* Wt = ws + WS_WT;
  float* part = ws + WS_PART;

  hipMemsetAsync(ws, 0, WS_WT * sizeof(float), stream);
  transpose_w<<<32, 256, 0, stream>>>(W, Wt);
  gate_gemm<<<1024, 256, 0, stream>>>(x, Wt, part);
  gate_epilogue<<<128, 128, 0, stream>>>(part, bias, out, Pacc, Cacc, counter);
}